// Round 1
// 853.489 us; speedup vs baseline: 1.5466x; 1.5466x over previous
//
#include <hip/hip_runtime.h>

// ConvMPN — N=2048, C=16, H=W=32, E=16384.
// R4: weight B-fragments precomputed once per layer (prep_wfrag) into a
// lane-ordered bf16 buffer. Previously every block rebuilt them with 144
// per-lane scalar fp32 loads striding 1728B -> 64 cache lines/instr ->
// ~9.2K vector-mem pipe cycles/wave ~= 88% of conv1's time. Now 9-18
// coalesced 16B/lane loads per thread.
// Pipeline: build_lists -> xpose(x->bf16 pixel-major) -> gather_enc
//   -> conv1 mfma (K=48 in 2 chunks of 32, zero-padded) -> h1 bf16 [px][32]
//   -> conv2 -> h2 -> conv3 -> out fp32 NCHW.
// LDS tile stride padded (72/40 ch) => 2-way bank aliasing only (free, m136).

#define NNODES 2048
#define HW 1024
#define PLANE 16384
#define CAP 128

typedef float v4f __attribute__((ext_vector_type(4)));
typedef short v8s __attribute__((ext_vector_type(8)));

__device__ inline unsigned short f2bfu(float f) {
    unsigned u = __float_as_uint(f);
    u += 0x7fffu + ((u >> 16) & 1u);   // round-to-nearest-even
    return (unsigned short)(u >> 16);
}
__device__ inline unsigned pk2(float a, float b) {
    return (unsigned)f2bfu(a) | ((unsigned)f2bfu(b) << 16);
}
__device__ inline void add2(float& a, float& b, unsigned u) {
    a += __uint_as_float(u << 16);
    b += __uint_as_float(u & 0xffff0000u);
}

// ---------------- adjacency lists ----------------
__global__ __launch_bounds__(256) void build_lists(
    const int* __restrict__ edges, int E, int* __restrict__ cnt, int* __restrict__ lists)
{
    int e = blockIdx.x * 256 + threadIdx.x;
    if (e >= E) return;
    int a = edges[3 * e + 0];
    int rel = edges[3 * e + 1];
    int b = edges[3 * e + 2];
    int s = (rel > 0) ? 0 : 1;
    int slot = atomicAdd(&cnt[b * 2 + s], 1);
    if (slot < CAP) lists[((size_t)(b * 2 + s)) * CAP + slot] = a;
    slot = atomicAdd(&cnt[a * 2 + s], 1);
    if (slot < CAP) lists[((size_t)(a * 2 + s)) * CAP + slot] = b;
}

// ---------------- x fp32 NCHW -> bf16 [n][1024 px][16 ch] ----------------
__global__ __launch_bounds__(256) void xpose_bf16(
    const float* __restrict__ x, ushort* __restrict__ xb)
{
    int n = blockIdx.x, t = threadIdx.x;
    const float4* src = (const float4*)(x + (size_t)n * PLANE);
    float vv[64];
#pragma unroll
    for (int i = 0; i < 16; i++) {
        float4 v = src[i * 256 + t];          // ci=i, pixels 4t..4t+3 (coalesced)
        vv[i * 4 + 0] = v.x; vv[i * 4 + 1] = v.y; vv[i * 4 + 2] = v.z; vv[i * 4 + 3] = v.w;
    }
    uint4* dst = (uint4*)(xb + (size_t)n * HW * 16);
#pragma unroll
    for (int j = 0; j < 4; j++) {
        uint4 o0, o1;
        o0.x = pk2(vv[0 * 4 + j], vv[1 * 4 + j]);
        o0.y = pk2(vv[2 * 4 + j], vv[3 * 4 + j]);
        o0.z = pk2(vv[4 * 4 + j], vv[5 * 4 + j]);
        o0.w = pk2(vv[6 * 4 + j], vv[7 * 4 + j]);
        o1.x = pk2(vv[8 * 4 + j], vv[9 * 4 + j]);
        o1.y = pk2(vv[10 * 4 + j], vv[11 * 4 + j]);
        o1.z = pk2(vv[12 * 4 + j], vv[13 * 4 + j]);
        o1.w = pk2(vv[14 * 4 + j], vv[15 * 4 + j]);
        dst[(4 * t + j) * 2 + 0] = o0;
        dst[(4 * t + j) * 2 + 1] = o1;
    }
}

// ---------------- gather -> enc bf16 [n][1024 px][64 ch] ----------------
// ch 0..15 = x, 16..31 = neigh, 32..47 = nonneigh, 48..63 = zeros (K-pad for mfma)
__global__ __launch_bounds__(256) void gather_enc(
    const ushort* __restrict__ xb, const int* __restrict__ cnt,
    const int* __restrict__ lists, ushort* __restrict__ enc)
{
    int v = blockIdx.x, t = threadIdx.x;
    __shared__ int slist[2 * CAP];
    __shared__ int sdeg[2];
    if (t < 2) sdeg[t] = min(cnt[v * 2 + t], CAP);
    slist[t] = lists[(size_t)v * 2 * CAP + t];   // 256 == 2*CAP
    __syncthreads();

    uint4* edst = (uint4*)(enc + (size_t)v * HW * 64);
    const uint4* xsrc = (const uint4*)(xb + (size_t)v * HW * 16);
    const uint4 z = make_uint4(0, 0, 0, 0);
#pragma unroll
    for (int j = 0; j < 4; j++) {
        int q = 4 * t + j;
        edst[q * 8 + 0] = xsrc[q * 2 + 0];
        edst[q * 8 + 1] = xsrc[q * 2 + 1];
        edst[q * 8 + 6] = z;
        edst[q * 8 + 7] = z;
    }
    for (int s = 0; s < 2; s++) {
        float acc[64];
#pragma unroll
        for (int i = 0; i < 64; i++) acc[i] = 0.f;
        int d = sdeg[s];
        for (int k = 0; k < d; k++) {
            const uint4* sp = (const uint4*)(xb + (size_t)slist[s * CAP + k] * HW * 16);
#pragma unroll
            for (int j = 0; j < 4; j++) {
                uint4 p0 = sp[(4 * t + j) * 2 + 0];
                uint4 p1 = sp[(4 * t + j) * 2 + 1];
                add2(acc[j * 16 + 0],  acc[j * 16 + 1],  p0.x);
                add2(acc[j * 16 + 2],  acc[j * 16 + 3],  p0.y);
                add2(acc[j * 16 + 4],  acc[j * 16 + 5],  p0.z);
                add2(acc[j * 16 + 6],  acc[j * 16 + 7],  p0.w);
                add2(acc[j * 16 + 8],  acc[j * 16 + 9],  p1.x);
                add2(acc[j * 16 + 10], acc[j * 16 + 11], p1.y);
                add2(acc[j * 16 + 12], acc[j * 16 + 13], p1.z);
                add2(acc[j * 16 + 14], acc[j * 16 + 15], p1.w);
            }
        }
#pragma unroll
        for (int j = 0; j < 4; j++) {
            uint4 o0, o1;
            o0.x = pk2(acc[j * 16 + 0],  acc[j * 16 + 1]);
            o0.y = pk2(acc[j * 16 + 2],  acc[j * 16 + 3]);
            o0.z = pk2(acc[j * 16 + 4],  acc[j * 16 + 5]);
            o0.w = pk2(acc[j * 16 + 6],  acc[j * 16 + 7]);
            o1.x = pk2(acc[j * 16 + 8],  acc[j * 16 + 9]);
            o1.y = pk2(acc[j * 16 + 10], acc[j * 16 + 11]);
            o1.z = pk2(acc[j * 16 + 12], acc[j * 16 + 13]);
            o1.w = pk2(acc[j * 16 + 14], acc[j * 16 + 15]);
            edst[(4 * t + j) * 8 + 2 + s * 2 + 0] = o0;
            edst[(4 * t + j) * 8 + 2 + s * 2 + 1] = o1;
        }
    }
}

// ---------------- weight B-fragment precompute ----------------
// wf layout: entry idx = ((cot*9 + khw)*KCH + kc)*64 + lane, each entry = 8 bf16
// (exactly the per-lane v8s the conv kernel consumes; coalesced 16B/lane load).
template<int CI_REAL, int KCH, int CO>
__global__ __launch_bounds__(256) void prep_wfrag(
    const float* __restrict__ wt, ushort* __restrict__ wf)
{
    const int total = (CO / 16) * 9 * KCH * 64;
    for (int idx = blockIdx.x * 256 + threadIdx.x; idx < total; idx += gridDim.x * 256) {
        int lane = idx & 63;
        int t = idx >> 6;
        int kc = t % KCH; t /= KCH;
        int khw = t % 9;  t /= 9;
        int cot = t;
        int nco = cot * 16 + (lane & 15);
        int kq  = lane >> 4;
        float w[8];
#pragma unroll
        for (int j = 0; j < 8; j++) {
            int k = kc * 32 + kq * 8 + j;
            w[j] = (k < CI_REAL) ? wt[((size_t)nco * CI_REAL + k) * 9 + khw] : 0.f;
        }
        uint4 o;
        o.x = pk2(w[0], w[1]); o.y = pk2(w[2], w[3]);
        o.z = pk2(w[4], w[5]); o.w = pk2(w[6], w[7]);
        *(uint4*)&wf[(size_t)idx * 8] = o;
    }
}

// ---------------- conv3x3 via bf16 MFMA 16x16x32 ----------------
// in: bf16 [n][1024][CIP_G]; out: bf16 [n][1024][CO] or fp32 NCHW.
// Block = quarter image (8 rows). LDS tile: 10 rows x 32 px x CIP_L (stride-padded).
// Wave loads its B-fragments (weights) from the precomputed wf buffer;
// A from LDS per (mtile,khw).
// MFMA layouts (m89/m118 verified): A m=lane&15,k=quad*8+j; B n=lane&15,k=quad*8+j;
//                                   D col(n)=lane&15, row(m)=quad*4+reg.
template<int CI_REAL, int CIP_G, int CIP_L, int KCH, int CO, bool OUT_F32>
__global__ __launch_bounds__(256) void conv_mfma(
    const ushort* __restrict__ in, const ushort* __restrict__ wf,
    const float* __restrict__ bias, ushort* __restrict__ outb,
    float* __restrict__ outf)
{
    __shared__ ushort tile[320 * CIP_L];
    const int n = blockIdx.x >> 2;
    const int r0 = (blockIdx.x & 3) * 8;
    const int CH4 = CIP_G / 8;                   // uint4 chunks per pixel

    const uint4* gsrc = (const uint4*)(in + (size_t)n * HW * CIP_G);
    for (int idx = threadIdx.x; idx < 320 * CH4; idx += 256) {
        int lp = idx / CH4;                      // local pixel 0..319 (10 rows x 32)
        int ch = idx - lp * CH4;
        int gr = r0 - 1 + (lp >> 5);
        uint4 val = make_uint4(0, 0, 0, 0);
        if (gr >= 0 && gr < 32) val = gsrc[(size_t)(gr * 32 + (lp & 31)) * CH4 + ch];
        *(uint4*)&tile[lp * CIP_L + ch * 8] = val;
    }
    __syncthreads();

    const int wv = threadIdx.x >> 6;
    const int lane = threadIdx.x & 63;
    const int l15 = lane & 15;
    const int kq = lane >> 4;                    // quad 0..3

    const int cotile = (CO == 32) ? (wv >> 1) : 0;
    const int cob = cotile * 16;
    const int nco = cob + l15;

    // B fragments: one per (khw, kchunk), coalesced 16B/lane loads from wf
    const v8s* wfv = (const v8s*)wf;
    v8s bfrag[9 * KCH];
#pragma unroll
    for (int khw = 0; khw < 9; khw++)
#pragma unroll
        for (int kc = 0; kc < KCH; kc++)
            bfrag[khw * KCH + kc] = wfv[(size_t)(((cotile * 9 + khw) * KCH + kc) * 64 + lane)];
    const float bv = bias[nco];

    int mt0, mtstep, nmt;
    if (CO == 32) { mt0 = wv & 1; mtstep = 2; nmt = 8; }
    else          { mt0 = wv;     mtstep = 4; nmt = 4; }

    for (int it = 0; it < nmt; it++) {
        int mtile = mt0 + it * mtstep;           // 16 px = half-row tiles
        int r = r0 + (mtile >> 1);
        int c = (mtile & 1) * 16 + l15;          // this lane's A-row pixel column
        v4f acc = {bv, bv, bv, bv};
#pragma unroll
        for (int khw = 0; khw < 9; khw++) {
            int dh = khw / 3 - 1, dw = (khw % 3) - 1;
            int rr = r + dh;
            if (rr < 0 || rr > 31) continue;     // wave-uniform (zero-pad row)
            int cc = c + dw;
            bool okc = (cc >= 0) && (cc <= 31);
            int lp = (rr - r0 + 1) * 32 + (okc ? cc : 0);
#pragma unroll
            for (int kc = 0; kc < KCH; kc++) {
                v8s a = *(const v8s*)&tile[lp * CIP_L + kc * 32 + kq * 8];
                if (!okc) a = (v8s)0;            // zero-pad column (per-lane)
                acc = __builtin_amdgcn_mfma_f32_16x16x32_bf16(a, bfrag[khw * KCH + kc], acc, 0, 0, 0);
            }
        }
        int pbase = r * 32 + (mtile & 1) * 16 + kq * 4;   // first pixel of this lane's 4 rows
        if (OUT_F32) {
            float4 o; o.x = acc[0]; o.y = acc[1]; o.z = acc[2]; o.w = acc[3];
            *(float4*)(outf + ((size_t)n * CO + nco) * HW + pbase) = o;
        } else {
#pragma unroll
            for (int reg = 0; reg < 4; reg++)
                outb[((size_t)n * HW + pbase + reg) * CO + nco] = (ushort)f2bfu(acc[reg]);
        }
    }
}

extern "C" void kernel_launch(void* const* d_in, const int* in_sizes, int n_in,
                              void* d_out, int out_size, void* d_ws, size_t ws_size,
                              hipStream_t stream)
{
    const float* x     = (const float*)d_in[0];
    const int*   edges = (const int*)d_in[1];
    const float* w1    = (const float*)d_in[2];
    const float* b1    = (const float*)d_in[3];
    const float* w2    = (const float*)d_in[4];
    const float* b2    = (const float*)d_in[5];
    const float* w3    = (const float*)d_in[6];
    const float* b3    = (const float*)d_in[7];
    float* out = (float*)d_out;

    const int E = in_sizes[1] / 3;   // 16384

    // ws layout (ushort units), ~450 MiB total:
    //   enc: [n][1024][64] bf16 (256 MiB)  -- reused as h2 after conv1
    //   h1:  [n][1024][32] bf16 (128 MiB)
    //   xb:  [n][1024][16] bf16 (64 MiB)
    //   cnt/lists: ints (~2 MiB)
    //   wf1/wf2/wf3: precomputed bf16 B-fragments (~64 KiB)
    ushort* enc = (ushort*)d_ws;
    ushort* h1  = enc + (size_t)NNODES * HW * 64;
    ushort* xb  = h1  + (size_t)NNODES * HW * 32;
    int*    cnt   = (int*)(xb + (size_t)NNODES * HW * 16);
    int*    lists = cnt + NNODES * 2;
    ushort* wf1 = (ushort*)(lists + (size_t)NNODES * 2 * CAP);
    ushort* wf2 = wf1 + 2 * 9 * 2 * 64 * 8;     // conv1: 2 cotiles, KCH=2
    ushort* wf3 = wf2 + 2 * 9 * 1 * 64 * 8;     // conv2: 2 cotiles, KCH=1
    ushort* h2  = enc;

    hipMemsetAsync(cnt, 0, NNODES * 2 * sizeof(int), stream);
    build_lists<<<(E + 255) / 256, 256, 0, stream>>>(edges, E, cnt, lists);

    // weight fragment precompute (tiny; L2-resident thereafter)
    prep_wfrag<48, 2, 32><<<9, 256, 0, stream>>>(w1, wf1);
    prep_wfrag<32, 1, 32><<<5, 256, 0, stream>>>(w2, wf2);
    prep_wfrag<32, 1, 16><<<3, 256, 0, stream>>>(w3, wf3);

    xpose_bf16<<<NNODES, 256, 0, stream>>>(x, xb);
    gather_enc<<<NNODES, 256, 0, stream>>>(xb, cnt, lists, enc);

    // conv1: 48 -> 32  (K chunks: 0..31 real, 32..63 = 16 real + 16 zero-pad)
    conv_mfma<48, 64, 72, 2, 32, false><<<NNODES * 4, 256, 0, stream>>>(enc, wf1, b1, h1, nullptr);
    // conv2: 32 -> 32
    conv_mfma<32, 32, 40, 1, 32, false><<<NNODES * 4, 256, 0, stream>>>(h1, wf2, b2, h2, nullptr);
    // conv3: 32 -> 16, fp32 NCHW output
    conv_mfma<32, 32, 40, 1, 16, true><<<NNODES * 4, 256, 0, stream>>>(h2, wf3, b3, nullptr, out);
}

// Round 2
// 694.502 us; speedup vs baseline: 1.9006x; 1.2289x over previous
//
#include <hip/hip_runtime.h>

// ConvMPN — N=2048, C=16, H=W=32, E=16384.
// R5: gather restructured as XCD-pinned pixel-slice passes.
//   - 32 slices x 32 px; slice%8 == blockIdx%8 so (assuming round-robin
//     block->XCD dispatch, m09/m157 heuristic) each XCD's L2 serves the 16x
//     re-reads of its 2 MiB slice working set. Old gather re-fetched ~628MB
//     post-L2 (whole 64MiB xb, random planes, ~2x effective L2 reuse).
//   - enc shrunk to 48 real channels (no zero quarter); conv1 zeroes the
//     A-fragment in-register for koff>=48 (kc==1 && kq>=2). enc write 256->192
//     MiB, conv1 read 256->192 MiB, conv1 LDS 46->35KB.
// R4: weight B-fragments precomputed per layer (prep_wfrag), lane-ordered.
// Pipeline: build_lists -> xpose(x->bf16 pixel-major) -> gather_enc_slice
//   -> conv1 mfma (K=48, 2 chunks) -> h1 -> conv2 -> h2 -> conv3 -> fp32 NCHW.

#define NNODES 2048
#define HW 1024
#define PLANE 16384
#define CAP 128
#define SLICE_PX 32
#define NSLICE 32
#define NPB 8   // nodes per gather block (256 thr / 32 px)

typedef float v4f __attribute__((ext_vector_type(4)));
typedef short v8s __attribute__((ext_vector_type(8)));

__device__ inline unsigned short f2bfu(float f) {
    unsigned u = __float_as_uint(f);
    u += 0x7fffu + ((u >> 16) & 1u);   // round-to-nearest-even
    return (unsigned short)(u >> 16);
}
__device__ inline unsigned pk2(float a, float b) {
    return (unsigned)f2bfu(a) | ((unsigned)f2bfu(b) << 16);
}
__device__ inline void add2(float& a, float& b, unsigned u) {
    a += __uint_as_float(u << 16);
    b += __uint_as_float(u & 0xffff0000u);
}

// ---------------- adjacency lists ----------------
__global__ __launch_bounds__(256) void build_lists(
    const int* __restrict__ edges, int E, int* __restrict__ cnt, int* __restrict__ lists)
{
    int e = blockIdx.x * 256 + threadIdx.x;
    if (e >= E) return;
    int a = edges[3 * e + 0];
    int rel = edges[3 * e + 1];
    int b = edges[3 * e + 2];
    int s = (rel > 0) ? 0 : 1;
    int slot = atomicAdd(&cnt[b * 2 + s], 1);
    if (slot < CAP) lists[((size_t)(b * 2 + s)) * CAP + slot] = a;
    slot = atomicAdd(&cnt[a * 2 + s], 1);
    if (slot < CAP) lists[((size_t)(a * 2 + s)) * CAP + slot] = b;
}

// ---------------- x fp32 NCHW -> bf16 [n][1024 px][16 ch] ----------------
__global__ __launch_bounds__(256) void xpose_bf16(
    const float* __restrict__ x, ushort* __restrict__ xb)
{
    int n = blockIdx.x, t = threadIdx.x;
    const float4* src = (const float4*)(x + (size_t)n * PLANE);
    float vv[64];
#pragma unroll
    for (int i = 0; i < 16; i++) {
        float4 v = src[i * 256 + t];          // ci=i, pixels 4t..4t+3 (coalesced)
        vv[i * 4 + 0] = v.x; vv[i * 4 + 1] = v.y; vv[i * 4 + 2] = v.z; vv[i * 4 + 3] = v.w;
    }
    uint4* dst = (uint4*)(xb + (size_t)n * HW * 16);
#pragma unroll
    for (int j = 0; j < 4; j++) {
        uint4 o0, o1;
        o0.x = pk2(vv[0 * 4 + j], vv[1 * 4 + j]);
        o0.y = pk2(vv[2 * 4 + j], vv[3 * 4 + j]);
        o0.z = pk2(vv[4 * 4 + j], vv[5 * 4 + j]);
        o0.w = pk2(vv[6 * 4 + j], vv[7 * 4 + j]);
        o1.x = pk2(vv[8 * 4 + j], vv[9 * 4 + j]);
        o1.y = pk2(vv[10 * 4 + j], vv[11 * 4 + j]);
        o1.z = pk2(vv[12 * 4 + j], vv[13 * 4 + j]);
        o1.w = pk2(vv[14 * 4 + j], vv[15 * 4 + j]);
        dst[(4 * t + j) * 2 + 0] = o0;
        dst[(4 * t + j) * 2 + 1] = o1;
    }
}

// ---------------- gather -> enc bf16 [n][1024 px][48 ch], slice-blocked ----
// ch 0..15 = x, 16..31 = neigh(+), 32..47 = nonneigh(-).
// Grid: 8192 blocks; idx = p*2048 + g*8 + x8; slice = p*8 + x8 (0..31).
// With round-robin block->XCD, XCD x8 only ever touches slices {x8, 8+x8, ...},
// whose 2 MiB per-slice working set (2048 nodes x 32 px x 32 B) is L2-resident.
__global__ __launch_bounds__(256) void gather_enc_slice(
    const ushort* __restrict__ xb, const int* __restrict__ cnt,
    const int* __restrict__ lists, ushort* __restrict__ enc)
{
    int idx = blockIdx.x;
    int x8 = idx & 7;
    int g  = (idx >> 3) & 255;
    int p  = idx >> 11;
    int slice = p * 8 + x8;
    int t = threadIdx.x;
    int node = g * NPB + (t >> 5);
    int px = slice * SLICE_PX + (t & 31);

    const uint4* xsrc = (const uint4*)(xb + ((size_t)node * HW + px) * 16);
    uint4* edst = (uint4*)(enc + ((size_t)node * HW + px) * 48);
    edst[0] = xsrc[0];
    edst[1] = xsrc[1];

    for (int s = 0; s < 2; s++) {
        int d = min(cnt[node * 2 + s], CAP);
        const int* lst = lists + (size_t)(node * 2 + s) * CAP;
        float acc[16];
#pragma unroll
        for (int i = 0; i < 16; i++) acc[i] = 0.f;
        int nb = (d > 0) ? lst[0] : 0;
        for (int k = 0; k < d; k++) {
            const uint4* sp = (const uint4*)(xb + ((size_t)nb * HW + px) * 16);
            uint4 p0 = sp[0];
            uint4 p1 = sp[1];
            nb = (k + 1 < d) ? lst[k + 1] : 0;   // prefetch next list entry
            add2(acc[0],  acc[1],  p0.x);
            add2(acc[2],  acc[3],  p0.y);
            add2(acc[4],  acc[5],  p0.z);
            add2(acc[6],  acc[7],  p0.w);
            add2(acc[8],  acc[9],  p1.x);
            add2(acc[10], acc[11], p1.y);
            add2(acc[12], acc[13], p1.z);
            add2(acc[14], acc[15], p1.w);
        }
        uint4 o0, o1;
        o0.x = pk2(acc[0],  acc[1]);  o0.y = pk2(acc[2],  acc[3]);
        o0.z = pk2(acc[4],  acc[5]);  o0.w = pk2(acc[6],  acc[7]);
        o1.x = pk2(acc[8],  acc[9]);  o1.y = pk2(acc[10], acc[11]);
        o1.z = pk2(acc[12], acc[13]); o1.w = pk2(acc[14], acc[15]);
        edst[2 + s * 2 + 0] = o0;
        edst[2 + s * 2 + 1] = o1;
    }
}

// ---------------- weight B-fragment precompute ----------------
// wf layout: entry idx = ((cot*9 + khw)*KCH + kc)*64 + lane, each entry = 8 bf16
// (exactly the per-lane v8s the conv kernel consumes; coalesced 16B/lane load).
template<int CI_REAL, int KCH, int CO>
__global__ __launch_bounds__(256) void prep_wfrag(
    const float* __restrict__ wt, ushort* __restrict__ wf)
{
    const int total = (CO / 16) * 9 * KCH * 64;
    for (int idx = blockIdx.x * 256 + threadIdx.x; idx < total; idx += gridDim.x * 256) {
        int lane = idx & 63;
        int t = idx >> 6;
        int kc = t % KCH; t /= KCH;
        int khw = t % 9;  t /= 9;
        int cot = t;
        int nco = cot * 16 + (lane & 15);
        int kq  = lane >> 4;
        float w[8];
#pragma unroll
        for (int j = 0; j < 8; j++) {
            int k = kc * 32 + kq * 8 + j;
            w[j] = (k < CI_REAL) ? wt[((size_t)nco * CI_REAL + k) * 9 + khw] : 0.f;
        }
        uint4 o;
        o.x = pk2(w[0], w[1]); o.y = pk2(w[2], w[3]);
        o.z = pk2(w[4], w[5]); o.w = pk2(w[6], w[7]);
        *(uint4*)&wf[(size_t)idx * 8] = o;
    }
}

// ---------------- conv3x3 via bf16 MFMA 16x16x32 ----------------
// in: bf16 [n][1024][CIP_G]; out: bf16 [n][1024][CO] or fp32 NCHW.
// Block = quarter image (8 rows). LDS tile: 10 rows x 32 px x CIP_L (stride-padded).
// Wave loads its B-fragments (weights) from the precomputed wf buffer;
// A from LDS per (mtile,khw). K positions >= CI_REAL zeroed in-register.
// MFMA layouts (m89/m118 verified): A m=lane&15,k=quad*8+j; B n=lane&15,k=quad*8+j;
//                                   D col(n)=lane&15, row(m)=quad*4+reg.
template<int CI_REAL, int CIP_G, int CIP_L, int KCH, int CO, bool OUT_F32>
__global__ __launch_bounds__(256) void conv_mfma(
    const ushort* __restrict__ in, const ushort* __restrict__ wf,
    const float* __restrict__ bias, ushort* __restrict__ outb,
    float* __restrict__ outf)
{
    __shared__ ushort tile[320 * CIP_L + 8];     // +8: kq=3 K-pad read at lp=319
    const int n = blockIdx.x >> 2;
    const int r0 = (blockIdx.x & 3) * 8;
    const int CH4 = CIP_G / 8;                   // uint4 chunks per pixel

    const uint4* gsrc = (const uint4*)(in + (size_t)n * HW * CIP_G);
    for (int idx = threadIdx.x; idx < 320 * CH4; idx += 256) {
        int lp = idx / CH4;                      // local pixel 0..319 (10 rows x 32)
        int ch = idx - lp * CH4;
        int gr = r0 - 1 + (lp >> 5);
        uint4 val = make_uint4(0, 0, 0, 0);
        if (gr >= 0 && gr < 32) val = gsrc[(size_t)(gr * 32 + (lp & 31)) * CH4 + ch];
        *(uint4*)&tile[lp * CIP_L + ch * 8] = val;
    }
    __syncthreads();

    const int wv = threadIdx.x >> 6;
    const int lane = threadIdx.x & 63;
    const int l15 = lane & 15;
    const int kq = lane >> 4;                    // quad 0..3

    const int cotile = (CO == 32) ? (wv >> 1) : 0;
    const int cob = cotile * 16;
    const int nco = cob + l15;

    // B fragments: one per (khw, kchunk), coalesced 16B/lane loads from wf
    const v8s* wfv = (const v8s*)wf;
    v8s bfrag[9 * KCH];
#pragma unroll
    for (int khw = 0; khw < 9; khw++)
#pragma unroll
        for (int kc = 0; kc < KCH; kc++)
            bfrag[khw * KCH + kc] = wfv[(size_t)(((cotile * 9 + khw) * KCH + kc) * 64 + lane)];
    const float bv = bias[nco];

    int mt0, mtstep, nmt;
    if (CO == 32) { mt0 = wv & 1; mtstep = 2; nmt = 8; }
    else          { mt0 = wv;     mtstep = 4; nmt = 4; }

    for (int it = 0; it < nmt; it++) {
        int mtile = mt0 + it * mtstep;           // 16 px = half-row tiles
        int r = r0 + (mtile >> 1);
        int c = (mtile & 1) * 16 + l15;          // this lane's A-row pixel column
        v4f acc = {bv, bv, bv, bv};
#pragma unroll
        for (int khw = 0; khw < 9; khw++) {
            int dh = khw / 3 - 1, dw = (khw % 3) - 1;
            int rr = r + dh;
            if (rr < 0 || rr > 31) continue;     // wave-uniform (zero-pad row)
            int cc = c + dw;
            bool okc = (cc >= 0) && (cc <= 31);
            int lp = (rr - r0 + 1) * 32 + (okc ? cc : 0);
#pragma unroll
            for (int kc = 0; kc < KCH; kc++) {
                v8s a = *(const v8s*)&tile[lp * CIP_L + kc * 32 + kq * 8];
                // zero-pad: out-of-image column, or K position beyond CI_REAL
                bool kok = (kc * 32 + 32 <= CI_REAL) || (kc * 32 + kq * 8 < CI_REAL);
                if (!okc || !kok) a = (v8s)0;
                acc = __builtin_amdgcn_mfma_f32_16x16x32_bf16(a, bfrag[khw * KCH + kc], acc, 0, 0, 0);
            }
        }
        int pbase = r * 32 + (mtile & 1) * 16 + kq * 4;   // first pixel of this lane's 4 rows
        if (OUT_F32) {
            float4 o; o.x = acc[0]; o.y = acc[1]; o.z = acc[2]; o.w = acc[3];
            *(float4*)(outf + ((size_t)n * CO + nco) * HW + pbase) = o;
        } else {
#pragma unroll
            for (int reg = 0; reg < 4; reg++)
                outb[((size_t)n * HW + pbase + reg) * CO + nco] = (ushort)f2bfu(acc[reg]);
        }
    }
}

extern "C" void kernel_launch(void* const* d_in, const int* in_sizes, int n_in,
                              void* d_out, int out_size, void* d_ws, size_t ws_size,
                              hipStream_t stream)
{
    const float* x     = (const float*)d_in[0];
    const int*   edges = (const int*)d_in[1];
    const float* w1    = (const float*)d_in[2];
    const float* b1    = (const float*)d_in[3];
    const float* w2    = (const float*)d_in[4];
    const float* b2    = (const float*)d_in[5];
    const float* w3    = (const float*)d_in[6];
    const float* b3    = (const float*)d_in[7];
    float* out = (float*)d_out;

    const int E = in_sizes[1] / 3;   // 16384

    // ws layout (ushort units), ~386 MiB total:
    //   enc: [n][1024][48] bf16 (192 MiB)  -- reused as h2 after conv1
    //   h1:  [n][1024][32] bf16 (128 MiB)
    //   xb:  [n][1024][16] bf16 (64 MiB)
    //   cnt/lists: ints (~2 MiB)
    //   wf1/wf2/wf3: precomputed bf16 B-fragments (~64 KiB)
    ushort* enc = (ushort*)d_ws;
    ushort* h1  = enc + (size_t)NNODES * HW * 48;
    ushort* xb  = h1  + (size_t)NNODES * HW * 32;
    int*    cnt   = (int*)(xb + (size_t)NNODES * HW * 16);
    int*    lists = cnt + NNODES * 2;
    ushort* wf1 = (ushort*)(lists + (size_t)NNODES * 2 * CAP);
    ushort* wf2 = wf1 + 2 * 9 * 2 * 64 * 8;     // conv1: 2 cotiles, KCH=2
    ushort* wf3 = wf2 + 2 * 9 * 1 * 64 * 8;     // conv2: 2 cotiles, KCH=1
    ushort* h2  = enc;

    hipMemsetAsync(cnt, 0, NNODES * 2 * sizeof(int), stream);
    build_lists<<<(E + 255) / 256, 256, 0, stream>>>(edges, E, cnt, lists);

    // weight fragment precompute (tiny; L2-resident thereafter)
    prep_wfrag<48, 2, 32><<<9, 256, 0, stream>>>(w1, wf1);
    prep_wfrag<32, 1, 32><<<5, 256, 0, stream>>>(w2, wf2);
    prep_wfrag<32, 1, 16><<<3, 256, 0, stream>>>(w3, wf3);

    xpose_bf16<<<NNODES, 256, 0, stream>>>(x, xb);
    gather_enc_slice<<<NSLICE * (NNODES / NPB), 256, 0, stream>>>(xb, cnt, lists, enc);

    // conv1: 48 -> 32  (K chunks: 32 + 16 real, rest zeroed in-register)
    conv_mfma<48, 48, 56, 2, 32, false><<<NNODES * 4, 256, 0, stream>>>(enc, wf1, b1, h1, nullptr);
    // conv2: 32 -> 32
    conv_mfma<32, 32, 40, 1, 32, false><<<NNODES * 4, 256, 0, stream>>>(h1, wf2, b2, h2, nullptr);
    // conv3: 32 -> 16, fp32 NCHW output
    conv_mfma<32, 32, 40, 1, 16, true><<<NNODES * 4, 256, 0, stream>>>(h2, wf3, b3, nullptr, out);
}